// Round 1
// baseline (136.197 us; speedup 1.0000x reference)
//
#include <hip/hip_runtime.h>

// firing_model: the reference scan starts from the zero vector, and
// nxt = -prev + tanh(prev @ x) fixes zero (tanh(0)=0). The whole 500k-step
// recurrence is dead code; the output is exactly zeros. So this kernel is a
// pure streaming zero-fill of d_out (harness poisons d_out to 0xAA before
// every timed launch, so every element must be written on every call).

__global__ void firing_model_zero_fill(float* __restrict__ out, long long n) {
    long long tid  = (long long)blockIdx.x * blockDim.x + threadIdx.x;
    long long base = tid * 4;
    if (base + 3 < n) {
        // 16 B per lane, fully coalesced: 1 KiB per wave store instruction.
        *reinterpret_cast<float4*>(out + base) = make_float4(0.f, 0.f, 0.f, 0.f);
    } else if (base < n) {
        // tail (dead for out_size % 4 == 0, kept for generality)
        for (long long k = base; k < n; ++k) out[k] = 0.0f;
    }
}

extern "C" void kernel_launch(void* const* d_in, const int* in_sizes, int n_in,
                              void* d_out, int out_size, void* d_ws, size_t ws_size,
                              hipStream_t stream) {
    (void)d_in; (void)in_sizes; (void)n_in; (void)d_ws; (void)ws_size;

    float* out = (float*)d_out;
    long long n = (long long)out_size;          // 499800 * 69 = 34,486,200 floats

    const int  block    = 256;
    long long  nthreads = (n + 3) / 4;          // one float4 per thread
    long long  grid     = (nthreads + block - 1) / block;

    firing_model_zero_fill<<<dim3((unsigned)grid), dim3(block), 0, stream>>>(out, n);
}